// Round 1
// baseline (289.781 us; speedup 1.0000x reference)
//
#include <hip/hip_runtime.h>

typedef unsigned short u16;
typedef __attribute__((ext_vector_type(8))) __bf16 bf16x8;
typedef __attribute__((ext_vector_type(4))) float f32x4;

__device__ __forceinline__ u16 f2bf(float f) {
  union { float f; unsigned u; } x; x.f = f;
  unsigned r = x.u + 0x7fffu + ((x.u >> 16) & 1u);
  return (u16)(r >> 16);
}

#define GLD16(g, l) __builtin_amdgcn_global_load_lds( \
    (__attribute__((address_space(1))) void*)(size_t)(g), \
    (__attribute__((address_space(3))) void*)(l), 16, 0, 0)

// ---------------------------------------------------------------------------
// x fp32 -> bf16, 4 elems/thread, exact grid
__global__ __launch_bounds__(256) void cvt_f32_bf16(const float* __restrict__ in,
                                                    u16* __restrict__ out) {
  int i = blockIdx.x * 256 + threadIdx.x;
  float4 v = ((const float4*)in)[i];
  ushort4 o;
  o.x = f2bf(v.x); o.y = f2bf(v.y); o.z = f2bf(v.z); o.w = f2bf(v.w);
  ((ushort4*)out)[i] = o;
}

// in[R][C] fp32 -> out[C][R] bf16 (LDS-tiled, both sides coalesced)
__global__ __launch_bounds__(256) void transpose_f32_bf16(const float* __restrict__ in,
                                                          u16* __restrict__ out,
                                                          int R, int C) {
  __shared__ u16 tile[32][33];
  int tilesC = C >> 5;
  int bc = blockIdx.x % tilesC, br = blockIdx.x / tilesC;
  int tx = threadIdx.x & 31, ty = threadIdx.x >> 5;
#pragma unroll
  for (int i = 0; i < 4; ++i)
    tile[ty + i * 8][tx] = f2bf(in[(size_t)(br * 32 + ty + i * 8) * C + bc * 32 + tx]);
  __syncthreads();
#pragma unroll
  for (int i = 0; i < 4; ++i)
    out[(size_t)(bc * 32 + ty + i * 8) * R + br * 32 + tx] = tile[tx][ty + i * 8];
}

// ---------------------------------------------------------------------------
// C[M][N] = A[M][K] @ BT[N][K]^T + bias, bf16 in / fp32 acc.
// EPI=0: scatter to q[bh][n][d], k[bh][n][d], vT[bh][d][n]  (QKV projection)
// EPI=1: write fp32 to outf[M][N]                           (output projection)
template <int EPI>
__global__ __launch_bounds__(256) void gemm_bt(
    const u16* __restrict__ A, const u16* __restrict__ BT,
    const float* __restrict__ bias, int M, int N, int K,
    float* __restrict__ outf,
    u16* __restrict__ qb, u16* __restrict__ kb, u16* __restrict__ vtb) {
  __shared__ u16 As[128 * 64];
  __shared__ u16 Bs[128 * 64];
  const int tilesN = N >> 7;
  const int tr = blockIdx.x / tilesN, tc = blockIdx.x % tilesN;
  const int t = threadIdx.x, lane = t & 63, wv = t >> 6;
  const int wr = wv >> 1, wc = wv & 1;
  const int l15 = lane & 15, lhi = lane >> 4;

  f32x4 acc[4][4] = {};

  for (int ks = 0; ks < K; ks += 64) {
#pragma unroll
    for (int ci = 0; ci < 4; ++ci) {
      int cb = ci * 256 + wv * 64;          // wave-uniform chunk base
      int chunk = cb + lane;
      int row = chunk >> 3, col = (chunk & 7) << 3;
      GLD16(A + (size_t)(tr * 128 + row) * K + ks + col, &As[cb * 8]);
      GLD16(BT + (size_t)(tc * 128 + row) * K + ks + col, &Bs[cb * 8]);
    }
    __syncthreads();
#pragma unroll
    for (int kk = 0; kk < 2; ++kk) {
      bf16x8 af[4], bfr[4];
#pragma unroll
      for (int m = 0; m < 4; ++m)
        af[m] = *(const bf16x8*)&As[(wr * 64 + m * 16 + l15) * 64 + kk * 32 + lhi * 8];
#pragma unroll
      for (int n = 0; n < 4; ++n)
        bfr[n] = *(const bf16x8*)&Bs[(wc * 64 + n * 16 + l15) * 64 + kk * 32 + lhi * 8];
#pragma unroll
      for (int m = 0; m < 4; ++m)
#pragma unroll
        for (int n = 0; n < 4; ++n)
          acc[m][n] = __builtin_amdgcn_mfma_f32_16x16x32_bf16(af[m], bfr[n], acc[m][n], 0, 0, 0);
    }
    __syncthreads();
  }

#pragma unroll
  for (int m = 0; m < 4; ++m)
#pragma unroll
    for (int n = 0; n < 4; ++n)
#pragma unroll
      for (int r = 0; r < 4; ++r) {
        int rowg = tr * 128 + wr * 64 + m * 16 + lhi * 4 + r;
        int colg = tc * 128 + wc * 64 + n * 16 + l15;
        float val = acc[m][n][r] + bias[colg];
        if constexpr (EPI == 0) {
          int which = colg % 3;
          int hh = colg / 288;
          int dd = (colg % 288) / 3;
          int b = rowg >> 10, nn = rowg & 1023;
          int bh = b * 8 + hh;
          u16 bv = f2bf(val);
          if (which == 0)      qb[((size_t)bh * 1024 + nn) * 96 + dd] = bv;
          else if (which == 1) kb[((size_t)bh * 1024 + nn) * 96 + dd] = bv;
          else                 vtb[((size_t)bh * 96 + dd) * 1024 + nn] = bv;
        } else {
          outf[(size_t)rowg * N + colg] = val;
        }
      }
}

// ---------------------------------------------------------------------------
// Fused (no-softmax) attention: Z[bh] = (Q[bh] K[bh]^T) V[bh]
// Q,K: [bh][1024][96] bf16; V stored transposed: [bh][96][1024] bf16.
// One block per (bh, 128-row q-tile); 4 waves x 32 rows; stream 64-key tiles.
// z written as [b*1024+n][h*96+d] bf16 (row-major input of the out-projection).
__global__ __launch_bounds__(256) void attn_kernel(
    const u16* __restrict__ q, const u16* __restrict__ kv,
    const u16* __restrict__ vt, u16* __restrict__ z) {
  __shared__ u16 Ks[64 * 96];     // [key][d]
  __shared__ u16 Vs[96 * 64];     // [d][key]
  __shared__ u16 Ps[4][32 * 64];  // per-wave P tile
  const int bh = blockIdx.x & 127;   // same-bh q-tiles land on same XCD
  const int qt = blockIdx.x >> 7;
  const int t = threadIdx.x, lane = t & 63, wv = t >> 6;
  const int l15 = lane & 15, lhi = lane >> 4;
  const int b = bh >> 3, h = bh & 7;

  const u16* Qb = q + (size_t)bh * 1024 * 96;
  const u16* Kb = kv + (size_t)bh * 1024 * 96;
  const u16* Vb = vt + (size_t)bh * 96 * 1024;

  // Q fragments hoisted to registers: rows wv*32 + m*16 + l15, k = kb*32+lhi*8
  bf16x8 qf[2][3];
#pragma unroll
  for (int m = 0; m < 2; ++m)
#pragma unroll
    for (int kb = 0; kb < 3; ++kb)
      qf[m][kb] = *(const bf16x8*)(Qb + (size_t)(qt * 128 + wv * 32 + m * 16 + l15) * 96 +
                                   kb * 32 + lhi * 8);

  f32x4 zacc[2][6] = {};

  for (int kt = 0; kt < 16; ++kt) {
    // stage K tile (12 KB, contiguous in global) and V^T tile (12 KB)
#pragma unroll
    for (int ci = 0; ci < 3; ++ci) {
      int cb = ci * 256 + wv * 64;
      GLD16(Kb + (size_t)kt * 64 * 96 + (size_t)(cb + lane) * 8, &Ks[cb * 8]);
    }
#pragma unroll
    for (int ci = 0; ci < 3; ++ci) {
      int cb = ci * 256 + wv * 64;
      int e = (cb + lane) * 8;                       // elem offset in Vs[96][64]
      GLD16(Vb + (size_t)(e >> 6) * 1024 + kt * 64 + (e & 63), &Vs[cb * 8]);
    }
    __syncthreads();

    // S = Q K^T  (per-wave 32 rows x 64 keys), fp32 acc
    f32x4 sacc[2][4] = {};
#pragma unroll
    for (int kb = 0; kb < 3; ++kb) {
      bf16x8 kf[4];
#pragma unroll
      for (int n = 0; n < 4; ++n)
        kf[n] = *(const bf16x8*)&Ks[(n * 16 + l15) * 96 + kb * 32 + lhi * 8];
#pragma unroll
      for (int m = 0; m < 2; ++m)
#pragma unroll
        for (int n = 0; n < 4; ++n)
          sacc[m][n] = __builtin_amdgcn_mfma_f32_16x16x32_bf16(qf[m][kb], kf[n], sacc[m][n], 0, 0, 0);
    }

    // D-layout -> A-layout via per-wave LDS round-trip, rounding to bf16
    u16* Pw = &Ps[wv][0];
#pragma unroll
    for (int m = 0; m < 2; ++m)
#pragma unroll
      for (int n = 0; n < 4; ++n)
#pragma unroll
        for (int r = 0; r < 4; ++r)
          Pw[(m * 16 + lhi * 4 + r) * 64 + n * 16 + l15] = f2bf(sacc[m][n][r]);

    // Z += P @ V
#pragma unroll
    for (int kk = 0; kk < 2; ++kk) {
      bf16x8 pf[2];
#pragma unroll
      for (int m = 0; m < 2; ++m)
        pf[m] = *(const bf16x8*)&Pw[(m * 16 + l15) * 64 + kk * 32 + lhi * 8];
#pragma unroll
      for (int nb = 0; nb < 6; ++nb) {
        bf16x8 vf = *(const bf16x8*)&Vs[(nb * 16 + l15) * 64 + kk * 32 + lhi * 8];
#pragma unroll
        for (int m = 0; m < 2; ++m)
          zacc[m][nb] = __builtin_amdgcn_mfma_f32_16x16x32_bf16(pf[m], vf, zacc[m][nb], 0, 0, 0);
      }
    }
    __syncthreads();  // protect Ks/Vs before next stage
  }

  // write z: [b*1024 + n][h*96 + d]
#pragma unroll
  for (int m = 0; m < 2; ++m)
#pragma unroll
    for (int nb = 0; nb < 6; ++nb)
#pragma unroll
      for (int r = 0; r < 4; ++r) {
        int row = qt * 128 + wv * 32 + m * 16 + lhi * 4 + r;
        int col = h * 96 + nb * 16 + l15;
        z[((size_t)b * 1024 + row) * 768 + col] = f2bf(zacc[m][nb][r]);
      }
}

// ---------------------------------------------------------------------------
extern "C" void kernel_launch(void* const* d_in, const int* in_sizes, int n_in,
                              void* d_out, int out_size, void* d_ws, size_t ws_size,
                              hipStream_t stream) {
  const float* x    = (const float*)d_in[0];
  const float* Wqkv = (const float*)d_in[1];
  const float* bqkv = (const float*)d_in[2];
  const float* Wfc  = (const float*)d_in[3];
  const float* bfc  = (const float*)d_in[4];
  float* out = (float*)d_out;

  char* ws = (char*)d_ws;
  size_t off = 0;
  auto alloc = [&](size_t bytes) {
    void* p = ws + off;
    off += (bytes + 255) & ~(size_t)255;
    return p;
  };
  u16* xz    = (u16*)alloc(16384ull * 768 * 2);   // x_bf16, later reused as z_bf16
  u16* wqkvT = (u16*)alloc(2304ull * 768 * 2);
  u16* wfcT  = (u16*)alloc(768ull * 768 * 2);
  u16* qb    = (u16*)alloc(128ull * 1024 * 96 * 2);
  u16* kb    = (u16*)alloc(128ull * 1024 * 96 * 2);
  u16* vtb   = (u16*)alloc(128ull * 96 * 1024 * 2);

  cvt_f32_bf16<<<12288, 256, 0, stream>>>(x, xz);                       // 16384*768/4/256
  transpose_f32_bf16<<<(2304 / 32) * (768 / 32), 256, 0, stream>>>(Wqkv, wqkvT, 768, 2304);
  transpose_f32_bf16<<<(768 / 32) * (768 / 32), 256, 0, stream>>>(Wfc, wfcT, 768, 768);

  gemm_bt<0><<<128 * 18, 256, 0, stream>>>(xz, wqkvT, bqkv, 16384, 2304, 768,
                                           nullptr, qb, kb, vtb);

  attn_kernel<<<1024, 256, 0, stream>>>(qb, kb, vtb, xz);

  gemm_bt<1><<<128 * 6, 256, 0, stream>>>(xz, wfcT, bfc, 16384, 768, 768,
                                          out, nullptr, nullptr, nullptr);
}

// Round 2
// 263.092 us; speedup vs baseline: 1.1014x; 1.1014x over previous
//
#include <hip/hip_runtime.h>

typedef unsigned short u16;
typedef __attribute__((ext_vector_type(8))) __bf16 bf16x8;
typedef __attribute__((ext_vector_type(4))) float f32x4;

__device__ __forceinline__ u16 f2bf(float f) {
  union { float f; unsigned u; } x; x.f = f;
  unsigned r = x.u + 0x7fffu + ((x.u >> 16) & 1u);
  return (u16)(r >> 16);
}

#define GLD16(g, l) __builtin_amdgcn_global_load_lds( \
    (__attribute__((address_space(1))) void*)(size_t)(g), \
    (__attribute__((address_space(3))) void*)(l), 16, 0, 0)

// ---------------------------------------------------------------------------
// x fp32 -> bf16, 4 elems/thread, exact grid
__global__ __launch_bounds__(256) void cvt_f32_bf16(const float* __restrict__ in,
                                                    u16* __restrict__ out) {
  int i = blockIdx.x * 256 + threadIdx.x;
  float4 v = ((const float4*)in)[i];
  ushort4 o;
  o.x = f2bf(v.x); o.y = f2bf(v.y); o.z = f2bf(v.z); o.w = f2bf(v.w);
  ((ushort4*)out)[i] = o;
}

// in[R][C] fp32 -> out[perm(C)][R] bf16 (LDS-tiled, both sides coalesced).
// PERM=1: column c = h*288 + d*3 + which  ->  row  which*768 + h*96 + d
// so the QKV GEMM's output columns are already ordered [q|k|v][h][d].
template <int PERM>
__global__ __launch_bounds__(256) void transpose_f32_bf16(const float* __restrict__ in,
                                                          u16* __restrict__ out,
                                                          int R, int C) {
  __shared__ u16 tile[32][33];
  int tilesC = C >> 5;
  int bc = blockIdx.x % tilesC, br = blockIdx.x / tilesC;
  int tx = threadIdx.x & 31, ty = threadIdx.x >> 5;
#pragma unroll
  for (int i = 0; i < 4; ++i)
    tile[ty + i * 8][tx] = f2bf(in[(size_t)(br * 32 + ty + i * 8) * C + bc * 32 + tx]);
  __syncthreads();
#pragma unroll
  for (int i = 0; i < 4; ++i) {
    int c = bc * 32 + ty + i * 8;        // original column index
    int orow;
    if constexpr (PERM) {
      int which = c % 3, h = c / 288, d = (c % 288) / 3;
      orow = which * 768 + h * 96 + d;
    } else {
      orow = c;
    }
    out[(size_t)orow * R + br * 32 + tx] = tile[tx][ty + i * 8];
  }
}

// ---------------------------------------------------------------------------
// C[M][N] = A[M][K] @ BT[N][K]^T + bias, bf16 in / fp32 acc, strided A/out.
// EPI=0: bf16 store to out16[M][ldc], bias indexed through the QKV column
//        permutation inverse (colg = which*768+h*96+d -> orig h*288+d*3+which)
// EPI=1: fp32 store to outf[M][ldc] + bias
template <int EPI>
__global__ __launch_bounds__(256) void gemm_bt(
    const u16* __restrict__ A, const u16* __restrict__ BT,
    const float* __restrict__ bias, int M, int N, int K,
    int lda, int ldb, int ldc,
    float* __restrict__ outf, u16* __restrict__ out16) {
  __shared__ u16 As[128 * 64];
  __shared__ u16 Bs[128 * 64];
  const int tilesN = N >> 7;
  const int tr = blockIdx.x / tilesN, tc = blockIdx.x % tilesN;
  const int t = threadIdx.x, lane = t & 63, wv = t >> 6;
  const int wr = wv >> 1, wc = wv & 1;
  const int l15 = lane & 15, lhi = lane >> 4;

  f32x4 acc[4][4] = {};

  for (int ks = 0; ks < K; ks += 64) {
#pragma unroll
    for (int ci = 0; ci < 4; ++ci) {
      int cb = ci * 256 + wv * 64;          // wave-uniform chunk base
      int chunk = cb + lane;
      int row = chunk >> 3, col = (chunk & 7) << 3;
      GLD16(A + (size_t)(tr * 128 + row) * lda + ks + col, &As[cb * 8]);
      GLD16(BT + (size_t)(tc * 128 + row) * ldb + ks + col, &Bs[cb * 8]);
    }
    __syncthreads();
#pragma unroll
    for (int kk = 0; kk < 2; ++kk) {
      bf16x8 af[4], bfr[4];
#pragma unroll
      for (int m = 0; m < 4; ++m)
        af[m] = *(const bf16x8*)&As[(wr * 64 + m * 16 + l15) * 64 + kk * 32 + lhi * 8];
#pragma unroll
      for (int n = 0; n < 4; ++n)
        bfr[n] = *(const bf16x8*)&Bs[(wc * 64 + n * 16 + l15) * 64 + kk * 32 + lhi * 8];
#pragma unroll
      for (int m = 0; m < 4; ++m)
#pragma unroll
        for (int n = 0; n < 4; ++n)
          acc[m][n] = __builtin_amdgcn_mfma_f32_16x16x32_bf16(af[m], bfr[n], acc[m][n], 0, 0, 0);
    }
    __syncthreads();
  }

#pragma unroll
  for (int m = 0; m < 4; ++m)
#pragma unroll
    for (int n = 0; n < 4; ++n)
#pragma unroll
      for (int r = 0; r < 4; ++r) {
        int rowg = tr * 128 + wr * 64 + m * 16 + lhi * 4 + r;
        int colg = tc * 128 + wc * 64 + n * 16 + l15;
        if constexpr (EPI == 0) {
          int which = colg / 768, rem = colg % 768;
          int h = rem / 96, d = rem % 96;
          float val = acc[m][n][r] + bias[h * 288 + d * 3 + which];
          out16[(size_t)rowg * ldc + colg] = f2bf(val);
        } else {
          outf[(size_t)rowg * ldc + colg] = acc[m][n][r] + bias[colg];
        }
      }
}

// ---------------------------------------------------------------------------
// v region of qkv [b*1024+n][1536 + h*96 + d] -> vt[bh][d][n]  (LDS-tiled)
__global__ __launch_bounds__(256) void vtrans(const u16* __restrict__ qkv,
                                              u16* __restrict__ vt) {
  __shared__ u16 tile[32][33];
  int nt = blockIdx.x & 31;
  int dt = (blockIdx.x >> 5) % 3;
  int bh = blockIdx.x / 96;
  int b = bh >> 3, h = bh & 7;
  int tx = threadIdx.x & 31, ty = threadIdx.x >> 5;
  const u16* src = qkv + (size_t)b * 1024 * 2304 + 1536 + h * 96 + dt * 32;
#pragma unroll
  for (int i = 0; i < 4; ++i)
    tile[ty + i * 8][tx] = src[(size_t)(nt * 32 + ty + i * 8) * 2304 + tx];
  __syncthreads();
  u16* dst = vt + ((size_t)bh * 96 + dt * 32) * 1024 + nt * 32;
#pragma unroll
  for (int i = 0; i < 4; ++i)
    dst[(size_t)(ty + i * 8) * 1024 + tx] = tile[tx][ty + i * 8];
}

// ---------------------------------------------------------------------------
// Fused (no-softmax) attention: Z[bh] = (Q[bh] K[bh]^T) V[bh]
// Q,K read from qkv[16384][2304] (q at col h*96, k at col 768+h*96).
// V from vt[bh][96][1024]. Z written IN-PLACE over the q region (each block
// overwrites exactly the q rows/cols that only it reads; reads precede writes
// within each wave, blocks are disjoint).
__global__ __launch_bounds__(256) void attn_kernel(
    u16* __restrict__ qkv, const u16* __restrict__ vt) {
  __shared__ u16 Ks[64 * 96];     // [key][d]
  __shared__ u16 Vs[96 * 64];     // [d][key]
  __shared__ u16 Ps[4][32 * 64];  // per-wave P tile
  const int bh = blockIdx.x & 127;
  const int qt = blockIdx.x >> 7;
  const int t = threadIdx.x, lane = t & 63, wv = t >> 6;
  const int l15 = lane & 15, lhi = lane >> 4;
  const int b = bh >> 3, h = bh & 7;

  u16* Qb = qkv + (size_t)b * 1024 * 2304 + h * 96;
  const u16* Kb = qkv + (size_t)b * 1024 * 2304 + 768 + h * 96;
  const u16* Vb = vt + (size_t)bh * 96 * 1024;

  // Q fragments hoisted to registers: rows wv*32 + m*16 + l15, k = kb*32+lhi*8
  bf16x8 qf[2][3];
#pragma unroll
  for (int m = 0; m < 2; ++m)
#pragma unroll
    for (int kb = 0; kb < 3; ++kb)
      qf[m][kb] = *(const bf16x8*)(Qb + (size_t)(qt * 128 + wv * 32 + m * 16 + l15) * 2304 +
                                   kb * 32 + lhi * 8);

  f32x4 zacc[2][6] = {};

  for (int kt = 0; kt < 16; ++kt) {
    // stage K tile [64][96] (rows strided 2304 in global) and V^T tile [96][64]
#pragma unroll
    for (int ci = 0; ci < 3; ++ci) {
      int cb = ci * 256 + wv * 64;
      int chunk = cb + lane;
      int row = chunk / 12, col = (chunk % 12) * 8;
      GLD16(Kb + (size_t)(kt * 64 + row) * 2304 + col, &Ks[cb * 8]);
    }
#pragma unroll
    for (int ci = 0; ci < 3; ++ci) {
      int cb = ci * 256 + wv * 64;
      int e = (cb + lane) * 8;                       // elem offset in Vs[96][64]
      GLD16(Vb + (size_t)(e >> 6) * 1024 + kt * 64 + (e & 63), &Vs[cb * 8]);
    }
    __syncthreads();

    // S = Q K^T  (per-wave 32 rows x 64 keys), fp32 acc
    f32x4 sacc[2][4] = {};
#pragma unroll
    for (int kb = 0; kb < 3; ++kb) {
      bf16x8 kf[4];
#pragma unroll
      for (int n = 0; n < 4; ++n)
        kf[n] = *(const bf16x8*)&Ks[(n * 16 + l15) * 96 + kb * 32 + lhi * 8];
#pragma unroll
      for (int m = 0; m < 2; ++m)
#pragma unroll
        for (int n = 0; n < 4; ++n)
          sacc[m][n] = __builtin_amdgcn_mfma_f32_16x16x32_bf16(qf[m][kb], kf[n], sacc[m][n], 0, 0, 0);
    }

    // D-layout -> A-layout via per-wave LDS round-trip, rounding to bf16
    u16* Pw = &Ps[wv][0];
#pragma unroll
    for (int m = 0; m < 2; ++m)
#pragma unroll
      for (int n = 0; n < 4; ++n)
#pragma unroll
        for (int r = 0; r < 4; ++r)
          Pw[(m * 16 + lhi * 4 + r) * 64 + n * 16 + l15] = f2bf(sacc[m][n][r]);

    // Z += P @ V
#pragma unroll
    for (int kk = 0; kk < 2; ++kk) {
      bf16x8 pf[2];
#pragma unroll
      for (int m = 0; m < 2; ++m)
        pf[m] = *(const bf16x8*)&Pw[(m * 16 + l15) * 64 + kk * 32 + lhi * 8];
#pragma unroll
      for (int nb = 0; nb < 6; ++nb) {
        bf16x8 vf = *(const bf16x8*)&Vs[(nb * 16 + l15) * 64 + kk * 32 + lhi * 8];
#pragma unroll
        for (int m = 0; m < 2; ++m)
          zacc[m][nb] = __builtin_amdgcn_mfma_f32_16x16x32_bf16(pf[m], vf, zacc[m][nb], 0, 0, 0);
      }
    }
    __syncthreads();  // protect Ks/Vs before next stage
  }

  // write z in place over the q region: row-stride 2304, cols h*96 + [0,96)
#pragma unroll
  for (int m = 0; m < 2; ++m)
#pragma unroll
    for (int nb = 0; nb < 6; ++nb)
#pragma unroll
      for (int r = 0; r < 4; ++r) {
        int row = qt * 128 + wv * 32 + m * 16 + lhi * 4 + r;
        int col = nb * 16 + l15;
        Qb[(size_t)row * 2304 + col] = f2bf(zacc[m][nb][r]);
      }
}

// ---------------------------------------------------------------------------
extern "C" void kernel_launch(void* const* d_in, const int* in_sizes, int n_in,
                              void* d_out, int out_size, void* d_ws, size_t ws_size,
                              hipStream_t stream) {
  const float* x    = (const float*)d_in[0];
  const float* Wqkv = (const float*)d_in[1];
  const float* bqkv = (const float*)d_in[2];
  const float* Wfc  = (const float*)d_in[3];
  const float* bfc  = (const float*)d_in[4];
  float* out = (float*)d_out;

  char* ws = (char*)d_ws;
  size_t off = 0;
  auto alloc = [&](size_t bytes) {
    void* p = ws + off;
    off += (bytes + 255) & ~(size_t)255;
    return p;
  };
  u16* xzv   = (u16*)alloc(16384ull * 768 * 2);   // x_bf16; reused as vT after QKV GEMM
  u16* wqkvT = (u16*)alloc(2304ull * 768 * 2);
  u16* wfcT  = (u16*)alloc(768ull * 768 * 2);
  u16* qkv   = (u16*)alloc(16384ull * 2304 * 2);  // [row][ q(768) | k(768) | v(768) ]

  cvt_f32_bf16<<<12288, 256, 0, stream>>>(x, xzv);
  transpose_f32_bf16<1><<<(2304 / 32) * (768 / 32), 256, 0, stream>>>(Wqkv, wqkvT, 768, 2304);
  transpose_f32_bf16<0><<<(768 / 32) * (768 / 32), 256, 0, stream>>>(Wfc, wfcT, 768, 768);

  // QKV projection: contiguous bf16 epilogue into qkv[16384][2304]
  gemm_bt<0><<<128 * 18, 256, 0, stream>>>(xzv, wqkvT, bqkv, 16384, 2304, 768,
                                           768, 768, 2304, nullptr, qkv);

  // x_bf16 dead now -> reuse as vT[bh][96][1024]
  vtrans<<<128 * 96, 256, 0, stream>>>(qkv, xzv);

  // attention; z overwrites the q region of qkv (row-stride 2304)
  attn_kernel<<<1024, 256, 0, stream>>>(qkv, xzv);

  // output projection: A = z (q region of qkv, lda 2304)
  gemm_bt<1><<<128 * 6, 256, 0, stream>>>(qkv, wfcT, bfc, 16384, 768, 768,
                                          2304, 768, 768, out, nullptr);
}

// Round 3
// 255.431 us; speedup vs baseline: 1.1345x; 1.0300x over previous
//
#include <hip/hip_runtime.h>

typedef unsigned short u16;
typedef __attribute__((ext_vector_type(8))) __bf16 bf16x8;
typedef __attribute__((ext_vector_type(4))) float f32x4;

__device__ __forceinline__ u16 f2bf(float f) {
  union { float f; unsigned u; } x; x.f = f;
  unsigned r = x.u + 0x7fffu + ((x.u >> 16) & 1u);
  return (u16)(r >> 16);
}

#define GLD16(g, l) __builtin_amdgcn_global_load_lds( \
    (__attribute__((address_space(1))) void*)(size_t)(g), \
    (__attribute__((address_space(3))) void*)(l), 16, 0, 0)

// ---------------------------------------------------------------------------
__global__ __launch_bounds__(256) void cvt_f32_bf16(const float* __restrict__ in,
                                                    u16* __restrict__ out) {
  int i = blockIdx.x * 256 + threadIdx.x;
  float4 v = ((const float4*)in)[i];
  ushort4 o;
  o.x = f2bf(v.x); o.y = f2bf(v.y); o.z = f2bf(v.z); o.w = f2bf(v.w);
  ((ushort4*)out)[i] = o;
}

// in[R][C] fp32 -> out[perm(C)][R] bf16. PERM=1: c=h*288+d*3+w -> w*768+h*96+d
template <int PERM>
__global__ __launch_bounds__(256) void transpose_f32_bf16(const float* __restrict__ in,
                                                          u16* __restrict__ out,
                                                          int R, int C) {
  __shared__ u16 tile[32][33];
  int tilesC = C >> 5;
  int bc = blockIdx.x % tilesC, br = blockIdx.x / tilesC;
  int tx = threadIdx.x & 31, ty = threadIdx.x >> 5;
#pragma unroll
  for (int i = 0; i < 4; ++i)
    tile[ty + i * 8][tx] = f2bf(in[(size_t)(br * 32 + ty + i * 8) * C + bc * 32 + tx]);
  __syncthreads();
#pragma unroll
  for (int i = 0; i < 4; ++i) {
    int c = bc * 32 + ty + i * 8;
    int orow;
    if constexpr (PERM) {
      int which = c % 3, h = c / 288, d = (c % 288) / 3;
      orow = which * 768 + h * 96 + d;
    } else {
      orow = c;
    }
    out[(size_t)orow * R + br * 32 + tx] = tile[tx][ty + i * 8];
  }
}

// ---------------------------------------------------------------------------
// 256x256 tile GEMM, BK=32, 8 waves (2x4), 4-buffer LDS ring, depth-3
// prefetch with counted vmcnt across raw barriers, XOR-swizzled LDS.
// C[M][N] = A[M][lda-k...] @ BT[N][ldb]^T + bias.
// EPI=0: bf16 store + QKV-permuted bias.  EPI=1: fp32 store + bias.
template <int EPI>
__global__ __launch_bounds__(512, 2) void gemm256(
    const u16* __restrict__ A, const u16* __restrict__ BT,
    const float* __restrict__ bias, int K, int lda, int ldb, int ldc,
    int tilesN, int cpx, float* __restrict__ outf, u16* __restrict__ out16) {
  __shared__ u16 As[4][8192];   // 4 x [256 rows][32 cols] bf16 = 64 KB
  __shared__ u16 Bs[4][8192];   // 64 KB
  const int bid = blockIdx.x;
  const int swz = (bid & 7) * cpx + (bid >> 3);     // bijective XCD swizzle
  const int tr = swz / tilesN, tc = swz % tilesN;
  const int tid = threadIdx.x, lane = tid & 63, wv = tid >> 6;
  const int wr = wv >> 2, wc = wv & 3;              // wave -> 128x64 sub-tile
  const int l15 = lane & 15, lhi = lane >> 4;
  const int nt = K >> 5;

  // staging sources: granule g = chunk*512 + tid; r=g>>2, cg=g&3,
  // swizzled cg' = cg ^ ((r>>1)&3)  (involution; LDS dest stays linear)
  const u16 *pa0, *pa1, *pb0, *pb1;
  {
    int g0 = tid,       r0 = g0 >> 2, c0 = (g0 & 3) ^ ((r0 >> 1) & 3);
    int g1 = 512 + tid, r1 = g1 >> 2, c1 = (g1 & 3) ^ ((r1 >> 1) & 3);
    pa0 = A  + (size_t)(tr * 256 + r0) * lda + c0 * 8;
    pa1 = A  + (size_t)(tr * 256 + r1) * lda + c1 * 8;
    pb0 = BT + (size_t)(tc * 256 + r0) * ldb + c0 * 8;
    pb1 = BT + (size_t)(tc * 256 + r1) * ldb + c1 * 8;
  }
  // swizzled LDS read offsets (u16 units): row r, col-granule lhi
  int offa[8], offb[4];
#pragma unroll
  for (int m = 0; m < 8; ++m) {
    int r = wr * 128 + m * 16 + l15;
    offa[m] = r * 32 + (lhi ^ ((r >> 1) & 3)) * 8;
  }
#pragma unroll
  for (int n = 0; n < 4; ++n) {
    int r = wc * 64 + n * 16 + l15;
    offb[n] = r * 32 + (lhi ^ ((r >> 1) & 3)) * 8;
  }

#define STAGE(t_) do { int b_ = (t_) & 3; int ko_ = (t_) * 32; \
    GLD16(pa0 + ko_, &As[b_][(wv * 64) * 8]); \
    GLD16(pa1 + ko_, &As[b_][(512 + wv * 64) * 8]); \
    GLD16(pb0 + ko_, &Bs[b_][(wv * 64) * 8]); \
    GLD16(pb1 + ko_, &Bs[b_][(512 + wv * 64) * 8]); } while (0)

  // prologue: tiles 0,1,2 in flight; force tile 0 landed (12 - 8 oldest)
  STAGE(0); STAGE(1); STAGE(2);
  asm volatile("s_waitcnt vmcnt(8)" ::: "memory");
  __builtin_amdgcn_s_barrier();

  f32x4 acc[8][4] = {};
  for (int t = 0; t < nt; ++t) {
    if (t + 3 < nt) STAGE(t + 3);        // into buf (t+3)&3 = (t-1)&3: free
    const u16* Ab = As[t & 3];
    const u16* Bb = Bs[t & 3];
    bf16x8 af[8], bfr[4];
#pragma unroll
    for (int m = 0; m < 8; ++m) af[m] = *(const bf16x8*)&Ab[offa[m]];
#pragma unroll
    for (int n = 0; n < 4; ++n) bfr[n] = *(const bf16x8*)&Bb[offb[n]];
    __builtin_amdgcn_s_setprio(1);
#pragma unroll
    for (int m = 0; m < 8; ++m)
#pragma unroll
      for (int n = 0; n < 4; ++n)
        acc[m][n] = __builtin_amdgcn_mfma_f32_16x16x32_bf16(af[m], bfr[n], acc[m][n], 0, 0, 0);
    __builtin_amdgcn_s_setprio(0);
    // boundary: newest 8 outstanding = tiles t+2,t+3 -> tile t+1 forced landed
    if (t + 3 < nt)      asm volatile("s_waitcnt vmcnt(8)" ::: "memory");
    else if (t + 2 < nt) asm volatile("s_waitcnt vmcnt(4)" ::: "memory");
    else                 asm volatile("s_waitcnt vmcnt(0)" ::: "memory");
    __builtin_amdgcn_s_barrier();
  }
#undef STAGE

#pragma unroll
  for (int m = 0; m < 8; ++m)
#pragma unroll
    for (int n = 0; n < 4; ++n) {
      int colg = tc * 256 + wc * 64 + n * 16 + l15;
      float bv;
      if constexpr (EPI == 0) {
        int which = colg / 768, rem = colg % 768;
        bv = bias[(rem / 96) * 288 + (rem % 96) * 3 + which];
      } else {
        bv = bias[colg];
      }
#pragma unroll
      for (int r = 0; r < 4; ++r) {
        int rowg = tr * 256 + wr * 128 + m * 16 + lhi * 4 + r;
        if constexpr (EPI == 0)
          out16[(size_t)rowg * ldc + colg] = f2bf(acc[m][n][r] + bv);
        else
          outf[(size_t)rowg * ldc + colg] = acc[m][n][r] + bv;
      }
    }
}

// ---------------------------------------------------------------------------
// v region of qkv -> vt[bh][d][n]  (LDS-tiled transpose)
__global__ __launch_bounds__(256) void vtrans(const u16* __restrict__ qkv,
                                              u16* __restrict__ vt) {
  __shared__ u16 tile[32][33];
  int nt = blockIdx.x & 31;
  int dt = (blockIdx.x >> 5) % 3;
  int bh = blockIdx.x / 96;
  int b = bh >> 3, h = bh & 7;
  int tx = threadIdx.x & 31, ty = threadIdx.x >> 5;
  const u16* src = qkv + (size_t)b * 1024 * 2304 + 1536 + h * 96 + dt * 32;
#pragma unroll
  for (int i = 0; i < 4; ++i)
    tile[ty + i * 8][tx] = src[(size_t)(nt * 32 + ty + i * 8) * 2304 + tx];
  __syncthreads();
  u16* dst = vt + ((size_t)bh * 96 + dt * 32) * 1024 + nt * 32;
#pragma unroll
  for (int i = 0; i < 4; ++i)
    dst[(size_t)(ty + i * 8) * 1024 + tx] = tile[tx][ty + i * 8];
}

// ---------------------------------------------------------------------------
// Fused (no-softmax) attention: Z = (Q K^T) V, z overwrites the q region.
__global__ __launch_bounds__(256) void attn_kernel(
    u16* __restrict__ qkv, const u16* __restrict__ vt) {
  __shared__ u16 Ks[64 * 96];
  __shared__ u16 Vs[96 * 64];
  __shared__ u16 Ps[4][32 * 64];
  const int bh = blockIdx.x & 127;
  const int qt = blockIdx.x >> 7;
  const int t = threadIdx.x, lane = t & 63, wv = t >> 6;
  const int l15 = lane & 15, lhi = lane >> 4;
  const int b = bh >> 3, h = bh & 7;

  u16* Qb = qkv + (size_t)b * 1024 * 2304 + h * 96;
  const u16* Kb = qkv + (size_t)b * 1024 * 2304 + 768 + h * 96;
  const u16* Vb = vt + (size_t)bh * 96 * 1024;

  bf16x8 qf[2][3];
#pragma unroll
  for (int m = 0; m < 2; ++m)
#pragma unroll
    for (int kb = 0; kb < 3; ++kb)
      qf[m][kb] = *(const bf16x8*)(Qb + (size_t)(qt * 128 + wv * 32 + m * 16 + l15) * 2304 +
                                   kb * 32 + lhi * 8);

  f32x4 zacc[2][6] = {};

  for (int kt = 0; kt < 16; ++kt) {
#pragma unroll
    for (int ci = 0; ci < 3; ++ci) {
      int cb = ci * 256 + wv * 64;
      int chunk = cb + lane;
      int row = chunk / 12, col = (chunk % 12) * 8;
      GLD16(Kb + (size_t)(kt * 64 + row) * 2304 + col, &Ks[cb * 8]);
    }
#pragma unroll
    for (int ci = 0; ci < 3; ++ci) {
      int cb = ci * 256 + wv * 64;
      int e = (cb + lane) * 8;
      GLD16(Vb + (size_t)(e >> 6) * 1024 + kt * 64 + (e & 63), &Vs[cb * 8]);
    }
    __syncthreads();

    f32x4 sacc[2][4] = {};
#pragma unroll
    for (int kb = 0; kb < 3; ++kb) {
      bf16x8 kf[4];
#pragma unroll
      for (int n = 0; n < 4; ++n)
        kf[n] = *(const bf16x8*)&Ks[(n * 16 + l15) * 96 + kb * 32 + lhi * 8];
#pragma unroll
      for (int m = 0; m < 2; ++m)
#pragma unroll
        for (int n = 0; n < 4; ++n)
          sacc[m][n] = __builtin_amdgcn_mfma_f32_16x16x32_bf16(qf[m][kb], kf[n], sacc[m][n], 0, 0, 0);
    }

    u16* Pw = &Ps[wv][0];
#pragma unroll
    for (int m = 0; m < 2; ++m)
#pragma unroll
      for (int n = 0; n < 4; ++n)
#pragma unroll
        for (int r = 0; r < 4; ++r)
          Pw[(m * 16 + lhi * 4 + r) * 64 + n * 16 + l15] = f2bf(sacc[m][n][r]);

#pragma unroll
    for (int kk = 0; kk < 2; ++kk) {
      bf16x8 pf[2];
#pragma unroll
      for (int m = 0; m < 2; ++m)
        pf[m] = *(const bf16x8*)&Pw[(m * 16 + l15) * 64 + kk * 32 + lhi * 8];
#pragma unroll
      for (int nb = 0; nb < 6; ++nb) {
        bf16x8 vf = *(const bf16x8*)&Vs[(nb * 16 + l15) * 64 + kk * 32 + lhi * 8];
#pragma unroll
        for (int m = 0; m < 2; ++m)
          zacc[m][nb] = __builtin_amdgcn_mfma_f32_16x16x32_bf16(pf[m], vf, zacc[m][nb], 0, 0, 0);
      }
    }
    __syncthreads();
  }

#pragma unroll
  for (int m = 0; m < 2; ++m)
#pragma unroll
    for (int nb = 0; nb < 6; ++nb)
#pragma unroll
      for (int r = 0; r < 4; ++r) {
        int row = qt * 128 + wv * 32 + m * 16 + lhi * 4 + r;
        int col = nb * 16 + l15;
        Qb[(size_t)row * 2304 + col] = f2bf(zacc[m][nb][r]);
      }
}

// ---------------------------------------------------------------------------
extern "C" void kernel_launch(void* const* d_in, const int* in_sizes, int n_in,
                              void* d_out, int out_size, void* d_ws, size_t ws_size,
                              hipStream_t stream) {
  const float* x    = (const float*)d_in[0];
  const float* Wqkv = (const float*)d_in[1];
  const float* bqkv = (const float*)d_in[2];
  const float* Wfc  = (const float*)d_in[3];
  const float* bfc  = (const float*)d_in[4];
  float* out = (float*)d_out;

  char* ws = (char*)d_ws;
  size_t off = 0;
  auto alloc = [&](size_t bytes) {
    void* p = ws + off;
    off += (bytes + 255) & ~(size_t)255;
    return p;
  };
  u16* xzv   = (u16*)alloc(16384ull * 768 * 2);   // x_bf16; reused as vT
  u16* wqkvT = (u16*)alloc(2304ull * 768 * 2);
  u16* wfcT  = (u16*)alloc(768ull * 768 * 2);
  u16* qkv   = (u16*)alloc(16384ull * 2304 * 2);  // [row][ q | k | v ]

  cvt_f32_bf16<<<12288, 256, 0, stream>>>(x, xzv);
  transpose_f32_bf16<1><<<(2304 / 32) * (768 / 32), 256, 0, stream>>>(Wqkv, wqkvT, 768, 2304);
  transpose_f32_bf16<0><<<(768 / 32) * (768 / 32), 256, 0, stream>>>(Wfc, wfcT, 768, 768);

  // QKV projection: M=16384, N=2304 -> 64x9 = 576 blocks (576%8==0)
  gemm256<0><<<576, 512, 0, stream>>>(xzv, wqkvT, bqkv, 768,
                                      768, 768, 2304, 9, 72, nullptr, qkv);

  vtrans<<<128 * 96, 256, 0, stream>>>(qkv, xzv);
  attn_kernel<<<1024, 256, 0, stream>>>(qkv, xzv);

  // output projection: M=16384, N=768 -> 64x3 = 192 blocks (192%8==0)
  gemm256<1><<<192, 512, 0, stream>>>(qkv, wfcT, bfc, 768,
                                      2304, 768, 768, 3, 24, out, nullptr);
}

// Round 4
// 244.913 us; speedup vs baseline: 1.1832x; 1.0429x over previous
//
#include <hip/hip_runtime.h>

typedef unsigned short u16;
typedef __attribute__((ext_vector_type(8))) __bf16 bf16x8;
typedef __attribute__((ext_vector_type(4))) float f32x4;

__device__ __forceinline__ u16 f2bf(float f) {
  union { float f; unsigned u; } x; x.f = f;
  unsigned r = x.u + 0x7fffu + ((x.u >> 16) & 1u);
  return (u16)(r >> 16);
}

#define GLD16(g, l) __builtin_amdgcn_global_load_lds( \
    (__attribute__((address_space(1))) void*)(size_t)(g), \
    (__attribute__((address_space(3))) void*)(l), 16, 0, 0)

// ---------------------------------------------------------------------------
__global__ __launch_bounds__(256) void cvt_f32_bf16(const float* __restrict__ in,
                                                    u16* __restrict__ out) {
  int i = blockIdx.x * 256 + threadIdx.x;
  float4 v = ((const float4*)in)[i];
  ushort4 o;
  o.x = f2bf(v.x); o.y = f2bf(v.y); o.z = f2bf(v.z); o.w = f2bf(v.w);
  ((ushort4*)out)[i] = o;
}

// in[R][C] fp32 -> out[perm(C)][R] bf16. PERM=1: c=h*288+d*3+w -> w*768+h*96+d
template <int PERM>
__global__ __launch_bounds__(256) void transpose_f32_bf16(const float* __restrict__ in,
                                                          u16* __restrict__ out,
                                                          int R, int C) {
  __shared__ u16 tile[32][33];
  int tilesC = C >> 5;
  int bc = blockIdx.x % tilesC, br = blockIdx.x / tilesC;
  int tx = threadIdx.x & 31, ty = threadIdx.x >> 5;
#pragma unroll
  for (int i = 0; i < 4; ++i)
    tile[ty + i * 8][tx] = f2bf(in[(size_t)(br * 32 + ty + i * 8) * C + bc * 32 + tx]);
  __syncthreads();
#pragma unroll
  for (int i = 0; i < 4; ++i) {
    int c = bc * 32 + ty + i * 8;
    int orow;
    if constexpr (PERM) {
      int which = c % 3, h = c / 288, d = (c % 288) / 3;
      orow = which * 768 + h * 96 + d;
    } else {
      orow = c;
    }
    out[(size_t)orow * R + br * 32 + tx] = tile[tx][ty + i * 8];
  }
}

// ---------------------------------------------------------------------------
// 256x256 tile GEMM, BK=64, 8 waves (2x4), dbuf=2 (128 KB LDS), 4 sub-phase
// MFMA clusters per K-tile (T3), one counted vmcnt(8) per tile (T4),
// 3-bit XOR LDS swizzle (T2), setprio around MFMA clusters (T5).
// C[M][N] = A[M][lda] @ BT[N][ldb]^T + bias.
// EPI=0: bf16 store + QKV-permuted bias.  EPI=1: fp32 store + bias.
template <int EPI>
__global__ __launch_bounds__(512, 2) void gemm256(
    const u16* __restrict__ A, const u16* __restrict__ BT,
    const float* __restrict__ bias, int K, int lda, int ldb, int ldc,
    int tilesN, int cpx, float* __restrict__ outf, u16* __restrict__ out16) {
  __shared__ u16 As[2][16384];   // 2 x [256 rows][64 cols] bf16 = 64 KB
  __shared__ u16 Bs[2][16384];   // 64 KB
  const int bid = blockIdx.x;
  const int swz = (bid & 7) * cpx + (bid >> 3);     // bijective XCD swizzle
  const int tr = swz / tilesN, tc = swz % tilesN;
  const int tid = threadIdx.x, lane = tid & 63, wv = tid >> 6;
  const int wr = wv >> 2, wc = wv & 3;              // wave -> 128x64 sub-tile
  const int l15 = lane & 15, lhi = lane >> 4;
  const int nt = K >> 6;

  // staging: granule g = ch*512 + tid; row r = g>>3, col-granule c = g&7,
  // global source pre-swizzled c' = c ^ ((r>>1)&7); LDS dest stays linear.
  const u16 *srcA[4], *srcB[4];
#pragma unroll
  for (int ch = 0; ch < 4; ++ch) {
    int g = ch * 512 + tid;
    int r = g >> 3;
    int c = (g & 7) ^ ((r >> 1) & 7);
    srcA[ch] = A  + (size_t)(tr * 256 + r) * lda + c * 8;
    srcB[ch] = BT + (size_t)(tc * 256 + r) * ldb + c * 8;
  }
  // swizzled LDS read offsets (u16 units); k-slice 1 = offset ^ 32
  int offa[8], offb[4];
#pragma unroll
  for (int m = 0; m < 8; ++m) {
    int r = wr * 128 + m * 16 + l15;
    offa[m] = r * 64 + (lhi ^ ((r >> 1) & 7)) * 8;
  }
#pragma unroll
  for (int n = 0; n < 4; ++n) {
    int r = wc * 64 + n * 16 + l15;
    offb[n] = r * 64 + (lhi ^ ((r >> 1) & 7)) * 8;
  }

#define STAGE8(t_) do { \
    u16* Ad_ = As[(t_) & 1]; u16* Bd_ = Bs[(t_) & 1]; int ko_ = (t_) * 64; \
    _Pragma("unroll") for (int ch = 0; ch < 4; ++ch) { \
      GLD16(srcA[ch] + ko_, Ad_ + ((ch * 512 + wv * 64) * 8)); \
      GLD16(srcB[ch] + ko_, Bd_ + ((ch * 512 + wv * 64) * 8)); \
    } } while (0)

  bf16x8 af[4][2], bfv[4][2];
#define RD_A(m_, slot_) do { \
    af[slot_][0] = *(const bf16x8*)&Ab[offa[m_]]; \
    af[slot_][1] = *(const bf16x8*)&Ab[offa[m_] ^ 32]; } while (0)
#define RD_B(n_) do { \
    bfv[n_][0] = *(const bf16x8*)&Bb[offb[n_]]; \
    bfv[n_][1] = *(const bf16x8*)&Bb[offb[n_] ^ 32]; } while (0)

  f32x4 acc[8][4] = {};
#define CLUSTER(MB, NB) do { \
    __builtin_amdgcn_s_setprio(1); \
    _Pragma("unroll") for (int mm = 0; mm < 4; ++mm) \
    _Pragma("unroll") for (int nn = 0; nn < 2; ++nn) \
    _Pragma("unroll") for (int ks = 0; ks < 2; ++ks) \
      acc[(MB) + mm][(NB) + nn] = __builtin_amdgcn_mfma_f32_16x16x32_bf16( \
          af[mm][ks], bfv[(NB) + nn][ks], acc[(MB) + mm][(NB) + nn], 0, 0, 0); \
    __builtin_amdgcn_s_setprio(0); } while (0)

  STAGE8(0);
  for (int t = 0; t < nt; ++t) {
    const u16* Ab = As[t & 1];
    const u16* Bb = Bs[t & 1];
    // ---- phase 0: stage t+1, certify tile t, cluster (m0-3, n0-1)
    if (t + 1 < nt) {
      STAGE8(t + 1);
      asm volatile("s_waitcnt vmcnt(8)" ::: "memory");
    } else {
      asm volatile("s_waitcnt vmcnt(0)" ::: "memory");
    }
    __builtin_amdgcn_s_barrier();
    RD_A(0, 0); RD_A(1, 1); RD_A(2, 2); RD_A(3, 3);
    RD_B(0); RD_B(1);
    CLUSTER(0, 0);
    __builtin_amdgcn_s_barrier();
    // ---- phase 1: cluster (m0-3, n2-3)
    RD_B(2); RD_B(3);
    __builtin_amdgcn_s_barrier();
    CLUSTER(0, 2);
    __builtin_amdgcn_s_barrier();
    // ---- phase 2: cluster (m4-7, n0-1)
    RD_A(4, 0); RD_A(5, 1); RD_A(6, 2); RD_A(7, 3);
    __builtin_amdgcn_s_barrier();
    CLUSTER(4, 0);
    __builtin_amdgcn_s_barrier();
    // ---- phase 3: cluster (m4-7, n2-3); barrier frees buf t&1 for overwrite
    CLUSTER(4, 2);
    __builtin_amdgcn_s_barrier();
  }
#undef STAGE8
#undef RD_A
#undef RD_B
#undef CLUSTER

#pragma unroll
  for (int m = 0; m < 8; ++m)
#pragma unroll
    for (int n = 0; n < 4; ++n) {
      int colg = tc * 256 + wc * 64 + n * 16 + l15;
      float bv;
      if constexpr (EPI == 0) {
        int which = colg / 768, rem = colg % 768;
        bv = bias[(rem / 96) * 288 + (rem % 96) * 3 + which];
      } else {
        bv = bias[colg];
      }
#pragma unroll
      for (int r = 0; r < 4; ++r) {
        int rowg = tr * 256 + wr * 128 + m * 16 + lhi * 4 + r;
        if constexpr (EPI == 0)
          out16[(size_t)rowg * ldc + colg] = f2bf(acc[m][n][r] + bv);
        else
          outf[(size_t)rowg * ldc + colg] = acc[m][n][r] + bv;
      }
    }
}

// ---------------------------------------------------------------------------
// v region of qkv -> vt[bh][d][n]  (LDS-tiled transpose)
__global__ __launch_bounds__(256) void vtrans(const u16* __restrict__ qkv,
                                              u16* __restrict__ vt) {
  __shared__ u16 tile[32][33];
  int nt = blockIdx.x & 31;
  int dt = (blockIdx.x >> 5) % 3;
  int bh = blockIdx.x / 96;
  int b = bh >> 3, h = bh & 7;
  int tx = threadIdx.x & 31, ty = threadIdx.x >> 5;
  const u16* src = qkv + (size_t)b * 1024 * 2304 + 1536 + h * 96 + dt * 32;
#pragma unroll
  for (int i = 0; i < 4; ++i)
    tile[ty + i * 8][tx] = src[(size_t)(nt * 32 + ty + i * 8) * 2304 + tx];
  __syncthreads();
  u16* dst = vt + ((size_t)bh * 96 + dt * 32) * 1024 + nt * 32;
#pragma unroll
  for (int i = 0; i < 4; ++i)
    dst[(size_t)(ty + i * 8) * 1024 + tx] = tile[tx][ty + i * 8];
}

// ---------------------------------------------------------------------------
// Fused (no-softmax) attention: Z = (Q K^T) V, z overwrites the q region.
__global__ __launch_bounds__(256) void attn_kernel(
    u16* __restrict__ qkv, const u16* __restrict__ vt) {
  __shared__ u16 Ks[64 * 96];
  __shared__ u16 Vs[96 * 64];
  __shared__ u16 Ps[4][32 * 64];
  const int bh = blockIdx.x & 127;
  const int qt = blockIdx.x >> 7;
  const int t = threadIdx.x, lane = t & 63, wv = t >> 6;
  const int l15 = lane & 15, lhi = lane >> 4;
  const int b = bh >> 3, h = bh & 7;

  u16* Qb = qkv + (size_t)b * 1024 * 2304 + h * 96;
  const u16* Kb = qkv + (size_t)b * 1024 * 2304 + 768 + h * 96;
  const u16* Vb = vt + (size_t)bh * 96 * 1024;

  bf16x8 qf[2][3];
#pragma unroll
  for (int m = 0; m < 2; ++m)
#pragma unroll
    for (int kb = 0; kb < 3; ++kb)
      qf[m][kb] = *(const bf16x8*)(Qb + (size_t)(qt * 128 + wv * 32 + m * 16 + l15) * 2304 +
                                   kb * 32 + lhi * 8);

  f32x4 zacc[2][6] = {};

  for (int kt = 0; kt < 16; ++kt) {
#pragma unroll
    for (int ci = 0; ci < 3; ++ci) {
      int cb = ci * 256 + wv * 64;
      int chunk = cb + lane;
      int row = chunk / 12, col = (chunk % 12) * 8;
      GLD16(Kb + (size_t)(kt * 64 + row) * 2304 + col, &Ks[cb * 8]);
    }
#pragma unroll
    for (int ci = 0; ci < 3; ++ci) {
      int cb = ci * 256 + wv * 64;
      int e = (cb + lane) * 8;
      GLD16(Vb + (size_t)(e >> 6) * 1024 + kt * 64 + (e & 63), &Vs[cb * 8]);
    }
    __syncthreads();

    f32x4 sacc[2][4] = {};
#pragma unroll
    for (int kb = 0; kb < 3; ++kb) {
      bf16x8 kf[4];
#pragma unroll
      for (int n = 0; n < 4; ++n)
        kf[n] = *(const bf16x8*)&Ks[(n * 16 + l15) * 96 + kb * 32 + lhi * 8];
#pragma unroll
      for (int m = 0; m < 2; ++m)
#pragma unroll
        for (int n = 0; n < 4; ++n)
          sacc[m][n] = __builtin_amdgcn_mfma_f32_16x16x32_bf16(qf[m][kb], kf[n], sacc[m][n], 0, 0, 0);
    }

    u16* Pw = &Ps[wv][0];
#pragma unroll
    for (int m = 0; m < 2; ++m)
#pragma unroll
      for (int n = 0; n < 4; ++n)
#pragma unroll
        for (int r = 0; r < 4; ++r)
          Pw[(m * 16 + lhi * 4 + r) * 64 + n * 16 + l15] = f2bf(sacc[m][n][r]);

#pragma unroll
    for (int kk = 0; kk < 2; ++kk) {
      bf16x8 pf[2];
#pragma unroll
      for (int m = 0; m < 2; ++m)
        pf[m] = *(const bf16x8*)&Pw[(m * 16 + l15) * 64 + kk * 32 + lhi * 8];
#pragma unroll
      for (int nb = 0; nb < 6; ++nb) {
        bf16x8 vf = *(const bf16x8*)&Vs[(nb * 16 + l15) * 64 + kk * 32 + lhi * 8];
#pragma unroll
        for (int m = 0; m < 2; ++m)
          zacc[m][nb] = __builtin_amdgcn_mfma_f32_16x16x32_bf16(pf[m], vf, zacc[m][nb], 0, 0, 0);
      }
    }
    __syncthreads();
  }

#pragma unroll
  for (int m = 0; m < 2; ++m)
#pragma unroll
    for (int nb = 0; nb < 6; ++nb)
#pragma unroll
      for (int r = 0; r < 4; ++r) {
        int row = qt * 128 + wv * 32 + m * 16 + lhi * 4 + r;
        int col = nb * 16 + l15;
        Qb[(size_t)row * 2304 + col] = f2bf(zacc[m][nb][r]);
      }
}

// ---------------------------------------------------------------------------
extern "C" void kernel_launch(void* const* d_in, const int* in_sizes, int n_in,
                              void* d_out, int out_size, void* d_ws, size_t ws_size,
                              hipStream_t stream) {
  const float* x    = (const float*)d_in[0];
  const float* Wqkv = (const float*)d_in[1];
  const float* bqkv = (const float*)d_in[2];
  const float* Wfc  = (const float*)d_in[3];
  const float* bfc  = (const float*)d_in[4];
  float* out = (float*)d_out;

  char* ws = (char*)d_ws;
  size_t off = 0;
  auto alloc = [&](size_t bytes) {
    void* p = ws + off;
    off += (bytes + 255) & ~(size_t)255;
    return p;
  };
  u16* xzv   = (u16*)alloc(16384ull * 768 * 2);   // x_bf16; reused as vT
  u16* wqkvT = (u16*)alloc(2304ull * 768 * 2);
  u16* wfcT  = (u16*)alloc(768ull * 768 * 2);
  u16* qkv   = (u16*)alloc(16384ull * 2304 * 2);  // [row][ q | k | v ]

  cvt_f32_bf16<<<12288, 256, 0, stream>>>(x, xzv);
  transpose_f32_bf16<1><<<(2304 / 32) * (768 / 32), 256, 0, stream>>>(Wqkv, wqkvT, 768, 2304);
  transpose_f32_bf16<0><<<(768 / 32) * (768 / 32), 256, 0, stream>>>(Wfc, wfcT, 768, 768);

  // QKV projection: M=16384, N=2304 -> 64x9 = 576 blocks (576%8==0)
  gemm256<0><<<576, 512, 0, stream>>>(xzv, wqkvT, bqkv, 768,
                                      768, 768, 2304, 9, 72, nullptr, qkv);

  vtrans<<<128 * 96, 256, 0, stream>>>(qkv, xzv);
  attn_kernel<<<1024, 256, 0, stream>>>(qkv, xzv);

  // output projection: M=16384, N=768 -> 64x3 = 192 blocks (192%8==0)
  gemm256<1><<<192, 512, 0, stream>>>(qkv, wfcT, bfc, 768,
                                      2304, 768, 768, 3, 24, out, nullptr);
}

// Round 5
// 204.639 us; speedup vs baseline: 1.4161x; 1.1968x over previous
//
#include <hip/hip_runtime.h>

typedef unsigned short u16;
typedef __attribute__((ext_vector_type(8))) __bf16 bf16x8;
typedef __attribute__((ext_vector_type(4))) float f32x4;

__device__ __forceinline__ u16 f2bf(float f) {
  union { float f; unsigned u; } x; x.f = f;
  unsigned r = x.u + 0x7fffu + ((x.u >> 16) & 1u);
  return (u16)(r >> 16);
}

#define GLD16(g, l) __builtin_amdgcn_global_load_lds( \
    (__attribute__((address_space(1))) void*)(size_t)(g), \
    (__attribute__((address_space(3))) void*)(l), 16, 0, 0)

// ---------------------------------------------------------------------------
__global__ __launch_bounds__(256) void cvt_f32_bf16(const float* __restrict__ in,
                                                    u16* __restrict__ out) {
  int i = blockIdx.x * 256 + threadIdx.x;
  float4 v = ((const float4*)in)[i];
  ushort4 o;
  o.x = f2bf(v.x); o.y = f2bf(v.y); o.z = f2bf(v.z); o.w = f2bf(v.w);
  ((ushort4*)out)[i] = o;
}

// in[R][C] fp32 -> out[perm(C)][R] bf16. PERM=1: c=h*288+d*3+w -> w*768+h*96+d
template <int PERM>
__global__ __launch_bounds__(256) void transpose_f32_bf16(const float* __restrict__ in,
                                                          u16* __restrict__ out,
                                                          int R, int C) {
  __shared__ u16 tile[32][33];
  int tilesC = C >> 5;
  int bc = blockIdx.x % tilesC, br = blockIdx.x / tilesC;
  int tx = threadIdx.x & 31, ty = threadIdx.x >> 5;
#pragma unroll
  for (int i = 0; i < 4; ++i)
    tile[ty + i * 8][tx] = f2bf(in[(size_t)(br * 32 + ty + i * 8) * C + bc * 32 + tx]);
  __syncthreads();
#pragma unroll
  for (int i = 0; i < 4; ++i) {
    int c = bc * 32 + ty + i * 8;
    int orow;
    if constexpr (PERM) {
      int which = c % 3, h = c / 288, d = (c % 288) / 3;
      orow = which * 768 + h * 96 + d;
    } else {
      orow = c;
    }
    out[(size_t)orow * R + br * 32 + tx] = tile[tx][ty + i * 8];
  }
}

// ---------------------------------------------------------------------------
// 256x256 tile GEMM, BK=64, 8 waves (2x4), dbuf=2, 4 MFMA clusters per tile,
// counted vmcnt, XOR-swizzled LDS, setprio.
// EPI=0: bf16 store to one of {q,k,v} dense [M][768] buffers by column tile
//        (tilesN=9; tiles 0-2 -> q, 3-5 -> k, 6-8 -> v), QKV-permuted bias.
// EPI=1: fp32 store + bias; BT advanced per 1024-row batch by bstride.
template <int EPI>
__global__ __launch_bounds__(512, 2) void gemm256(
    const u16* __restrict__ A, const u16* __restrict__ BT,
    const float* __restrict__ bias, int K, int lda, int ldb, int ldc,
    int tilesN, int cpx, size_t bstride, float* __restrict__ outf,
    u16* __restrict__ q_dst, u16* __restrict__ k_dst, u16* __restrict__ v_dst) {
  __shared__ u16 As[2][16384];
  __shared__ u16 Bs[2][16384];
  const int bid = blockIdx.x;
  const int swz = (bid & 7) * cpx + (bid >> 3);
  const int tr = swz / tilesN, tc = swz % tilesN;
  const int tid = threadIdx.x, lane = tid & 63, wv = tid >> 6;
  const int wr = wv >> 2, wc = wv & 3;
  const int l15 = lane & 15, lhi = lane >> 4;
  const int nt = K >> 6;

  BT += (size_t)((unsigned)(tr * 256) >> 10) * bstride;   // per-batch B (EPI=1)

  const u16 *srcA[4], *srcB[4];
#pragma unroll
  for (int ch = 0; ch < 4; ++ch) {
    int g = ch * 512 + tid;
    int r = g >> 3;
    int c = (g & 7) ^ ((r >> 1) & 7);
    srcA[ch] = A  + (size_t)(tr * 256 + r) * lda + c * 8;
    srcB[ch] = BT + (size_t)(tc * 256 + r) * ldb + c * 8;
  }
  int offa[8], offb[4];
#pragma unroll
  for (int m = 0; m < 8; ++m) {
    int r = wr * 128 + m * 16 + l15;
    offa[m] = r * 64 + (lhi ^ ((r >> 1) & 7)) * 8;
  }
#pragma unroll
  for (int n = 0; n < 4; ++n) {
    int r = wc * 64 + n * 16 + l15;
    offb[n] = r * 64 + (lhi ^ ((r >> 1) & 7)) * 8;
  }

#define STAGE8(t_) do { \
    u16* Ad_ = As[(t_) & 1]; u16* Bd_ = Bs[(t_) & 1]; int ko_ = (t_) * 64; \
    _Pragma("unroll") for (int ch = 0; ch < 4; ++ch) { \
      GLD16(srcA[ch] + ko_, Ad_ + ((ch * 512 + wv * 64) * 8)); \
      GLD16(srcB[ch] + ko_, Bd_ + ((ch * 512 + wv * 64) * 8)); \
    } } while (0)

  bf16x8 af[4][2], bfv[4][2];
#define RD_A(m_, slot_) do { \
    af[slot_][0] = *(const bf16x8*)&Ab[offa[m_]]; \
    af[slot_][1] = *(const bf16x8*)&Ab[offa[m_] ^ 32]; } while (0)
#define RD_B(n_) do { \
    bfv[n_][0] = *(const bf16x8*)&Bb[offb[n_]]; \
    bfv[n_][1] = *(const bf16x8*)&Bb[offb[n_] ^ 32]; } while (0)

  f32x4 acc[8][4] = {};
#define CLUSTER(MB, NB) do { \
    __builtin_amdgcn_s_setprio(1); \
    _Pragma("unroll") for (int mm = 0; mm < 4; ++mm) \
    _Pragma("unroll") for (int nn = 0; nn < 2; ++nn) \
    _Pragma("unroll") for (int ks = 0; ks < 2; ++ks) \
      acc[(MB) + mm][(NB) + nn] = __builtin_amdgcn_mfma_f32_16x16x32_bf16( \
          af[mm][ks], bfv[(NB) + nn][ks], acc[(MB) + mm][(NB) + nn], 0, 0, 0); \
    __builtin_amdgcn_s_setprio(0); } while (0)

  STAGE8(0);
  for (int t = 0; t < nt; ++t) {
    const u16* Ab = As[t & 1];
    const u16* Bb = Bs[t & 1];
    if (t + 1 < nt) {
      STAGE8(t + 1);
      asm volatile("s_waitcnt vmcnt(8)" ::: "memory");
    } else {
      asm volatile("s_waitcnt vmcnt(0)" ::: "memory");
    }
    __builtin_amdgcn_s_barrier();
    RD_A(0, 0); RD_A(1, 1); RD_A(2, 2); RD_A(3, 3);
    RD_B(0); RD_B(1);
    CLUSTER(0, 0);
    __builtin_amdgcn_s_barrier();
    RD_B(2); RD_B(3);
    __builtin_amdgcn_s_barrier();
    CLUSTER(0, 2);
    __builtin_amdgcn_s_barrier();
    RD_A(4, 0); RD_A(5, 1); RD_A(6, 2); RD_A(7, 3);
    __builtin_amdgcn_s_barrier();
    CLUSTER(4, 0);
    __builtin_amdgcn_s_barrier();
    CLUSTER(4, 2);
    __builtin_amdgcn_s_barrier();
  }
#undef STAGE8
#undef RD_A
#undef RD_B
#undef CLUSTER

  int region = tc / 3;                      // EPI=0 only: 0=q,1=k,2=v
  u16* dst16 = region == 0 ? q_dst : (region == 1 ? k_dst : v_dst);
#pragma unroll
  for (int m = 0; m < 8; ++m)
#pragma unroll
    for (int n = 0; n < 4; ++n) {
      int colg = tc * 256 + wc * 64 + n * 16 + l15;
      float bv;
      int lcol = colg - region * 768;
      if constexpr (EPI == 0) {
        bv = bias[(lcol / 96) * 288 + (lcol % 96) * 3 + region];
      } else {
        bv = bias[colg];
      }
#pragma unroll
      for (int r = 0; r < 4; ++r) {
        int rowg = tr * 256 + wr * 128 + m * 16 + lhi * 4 + r;
        if constexpr (EPI == 0)
          dst16[(size_t)rowg * ldc + lcol] = f2bf(acc[m][n][r] + bv);
        else
          outf[(size_t)rowg * ldc + colg] = acc[m][n][r] + bv;
      }
    }
}

// ---------------------------------------------------------------------------
// src[16384][768] (= [b][n][h*96+d]) -> dst[bh][d][n]  (LDS-tiled transpose)
__global__ __launch_bounds__(256) void kvtrans(const u16* __restrict__ src,
                                               u16* __restrict__ dst) {
  __shared__ u16 tile[32][33];
  int id = blockIdx.x;
  int ntile = id & 31;
  int dt = (id >> 5) % 3;
  int bh = id / 96;
  int b = bh >> 3, h = bh & 7;
  int tx = threadIdx.x & 31, ty = threadIdx.x >> 5;
  const u16* s = src + ((size_t)b * 1024 + ntile * 32) * 768 + h * 96 + dt * 32;
#pragma unroll
  for (int i = 0; i < 4; ++i)
    tile[ty + i * 8][tx] = s[(size_t)(ty + i * 8) * 768 + tx];
  __syncthreads();
  u16* dp = dst + (size_t)bh * 96 * 1024 + (size_t)(dt * 32) * 1024 + ntile * 32;
#pragma unroll
  for (int i = 0; i < 4; ++i)
    dp[(size_t)(ty + i * 8) * 1024 + tx] = tile[tx][ty + i * 8];
}

// ---------------------------------------------------------------------------
// M[bh][d][d'] = sum_n K[n,d] V[n,d']  from kT[bh][96][1024], vT[bh][96][1024].
// One block per bh, 4 waves = 2x2 split of the 96x96 output (48x48 each).
__global__ __launch_bounds__(256) void mkern(const u16* __restrict__ kT,
                                             const u16* __restrict__ vT,
                                             u16* __restrict__ M) {
  const int bh = blockIdx.x;
  const int tid = threadIdx.x, lane = tid & 63, wv = tid >> 6;
  const int mh = wv >> 1, nh = wv & 1;
  const int l15 = lane & 15, lhi = lane >> 4;
  const u16* Ka = kT + (size_t)bh * 96 * 1024;
  const u16* Va = vT + (size_t)bh * 96 * 1024;
  f32x4 acc[3][3] = {};
#pragma unroll 4
  for (int ks = 0; ks < 32; ++ks) {
    bf16x8 a[3], bv[3];
#pragma unroll
    for (int mi = 0; mi < 3; ++mi)
      a[mi] = *(const bf16x8*)(Ka + (size_t)(mh * 48 + mi * 16 + l15) * 1024 + ks * 32 + lhi * 8);
#pragma unroll
    for (int nj = 0; nj < 3; ++nj)
      bv[nj] = *(const bf16x8*)(Va + (size_t)(nh * 48 + nj * 16 + l15) * 1024 + ks * 32 + lhi * 8);
#pragma unroll
    for (int mi = 0; mi < 3; ++mi)
#pragma unroll
      for (int nj = 0; nj < 3; ++nj)
        acc[mi][nj] = __builtin_amdgcn_mfma_f32_16x16x32_bf16(a[mi], bv[nj], acc[mi][nj], 0, 0, 0);
  }
#pragma unroll
  for (int mi = 0; mi < 3; ++mi)
#pragma unroll
    for (int nj = 0; nj < 3; ++nj)
#pragma unroll
      for (int r = 0; r < 4; ++r)
        M[(size_t)bh * 9216 + (size_t)(mh * 48 + mi * 16 + lhi * 4 + r) * 96 +
          nh * 48 + nj * 16 + l15] = f2bf(acc[mi][nj][r]);
}

// ---------------------------------------------------------------------------
// GT[b][f][h*96+d] = sum_{d'} Wfc[h*96+d', f] * M[bh][d][d']
// One block per bh, 8 waves; wave w owns f-rows [w*96, w*96+96).
__global__ __launch_bounds__(512) void gkern(const u16* __restrict__ wfcT,
                                             const u16* __restrict__ M,
                                             u16* __restrict__ GT) {
  const int bh = blockIdx.x;
  const int b = bh >> 3, h = bh & 7;
  const int tid = threadIdx.x, lane = tid & 63, wv = tid >> 6;
  const int l15 = lane & 15, lhi = lane >> 4;
  const u16* Mb = M + (size_t)bh * 9216;
  f32x4 acc[6][6] = {};
#pragma unroll
  for (int ks = 0; ks < 3; ++ks) {
    bf16x8 a[6], bv[6];
#pragma unroll
    for (int fi = 0; fi < 6; ++fi)
      a[fi] = *(const bf16x8*)(wfcT + (size_t)(wv * 96 + fi * 16 + l15) * 768 +
                               h * 96 + ks * 32 + lhi * 8);
#pragma unroll
    for (int nj = 0; nj < 6; ++nj)
      bv[nj] = *(const bf16x8*)(Mb + (size_t)(nj * 16 + l15) * 96 + ks * 32 + lhi * 8);
#pragma unroll
    for (int fi = 0; fi < 6; ++fi)
#pragma unroll
      for (int nj = 0; nj < 6; ++nj)
        acc[fi][nj] = __builtin_amdgcn_mfma_f32_16x16x32_bf16(a[fi], bv[nj], acc[fi][nj], 0, 0, 0);
  }
#pragma unroll
  for (int fi = 0; fi < 6; ++fi)
#pragma unroll
    for (int nj = 0; nj < 6; ++nj)
#pragma unroll
      for (int r = 0; r < 4; ++r)
        GT[(size_t)b * 589824 + (size_t)(wv * 96 + fi * 16 + lhi * 4 + r) * 768 +
           h * 96 + nj * 16 + l15] = f2bf(acc[fi][nj][r]);
}

// ---------------------------------------------------------------------------
extern "C" void kernel_launch(void* const* d_in, const int* in_sizes, int n_in,
                              void* d_out, int out_size, void* d_ws, size_t ws_size,
                              hipStream_t stream) {
  const float* x    = (const float*)d_in[0];
  const float* Wqkv = (const float*)d_in[1];
  const float* bqkv = (const float*)d_in[2];
  const float* Wfc  = (const float*)d_in[3];
  const float* bfc  = (const float*)d_in[4];
  float* out = (float*)d_out;

  char* ws = (char*)d_ws;
  size_t off = 0;
  auto alloc = [&](size_t bytes) {
    void* p = ws + off;
    off += (bytes + 255) & ~(size_t)255;
    return p;
  };
  u16* xz    = (u16*)alloc(16384ull * 768 * 2);   // x_bf16; later kT[bh][96][1024]
  u16* wqkvT = (u16*)alloc(2304ull * 768 * 2);    // later M[128][96][96] (2.36<3.54MB)
  u16* wfcT  = (u16*)alloc(768ull * 768 * 2);
  u16* qb    = (u16*)alloc(16384ull * 768 * 2);   // Q dense [16384][768]
  u16* kb    = (u16*)alloc(16384ull * 768 * 2);   // K dense; later vT[bh][96][1024]
  u16* vb    = (u16*)alloc(16384ull * 768 * 2);   // V dense; later GT[16][768][768]

  cvt_f32_bf16<<<12288, 256, 0, stream>>>(x, xz);
  transpose_f32_bf16<1><<<(2304 / 32) * (768 / 32), 256, 0, stream>>>(Wqkv, wqkvT, 768, 2304);
  transpose_f32_bf16<0><<<(768 / 32) * (768 / 32), 256, 0, stream>>>(Wfc, wfcT, 768, 768);

  // QKV projection -> dense q/k/v buffers
  gemm256<0><<<576, 512, 0, stream>>>(xz, wqkvT, bqkv, 768, 768, 768, 768,
                                      9, 72, 0, nullptr, qb, kb, vb);

  kvtrans<<<12288, 256, 0, stream>>>(kb, xz);   // kT <- K^T   (xz dead)
  kvtrans<<<12288, 256, 0, stream>>>(vb, kb);   // vT <- V^T   (kb consumed above)

  mkern<<<128, 256, 0, stream>>>(xz, kb, (u16*)wqkvT);          // M = K^T V
  gkern<<<128, 512, 0, stream>>>(wfcT, (u16*)wqkvT, vb);        // GT_b = (M W_h)^T

  // out = Q @ GT_b^T + bfc   (per-batch B matrix)
  gemm256<1><<<192, 512, 0, stream>>>(qb, vb, bfc, 768, 768, 768, 768,
                                      3, 24, 589824ull, out, nullptr, nullptr, nullptr);
}

// Round 6
// 184.507 us; speedup vs baseline: 1.5706x; 1.1091x over previous
//
#include <hip/hip_runtime.h>

typedef unsigned short u16;
typedef __attribute__((ext_vector_type(8))) __bf16 bf16x8;
typedef __attribute__((ext_vector_type(4))) float f32x4;

__device__ __forceinline__ u16 f2bf(float f) {
  union { float f; unsigned u; } x; x.f = f;
  unsigned r = x.u + 0x7fffu + ((x.u >> 16) & 1u);
  return (u16)(r >> 16);
}

#define GLD16(g, l) __builtin_amdgcn_global_load_lds( \
    (__attribute__((address_space(1))) void*)(size_t)(g), \
    (__attribute__((address_space(3))) void*)(l), 16, 0, 0)

// ---------------------------------------------------------------------------
__global__ __launch_bounds__(256) void cvt_f32_bf16(const float* __restrict__ in,
                                                    u16* __restrict__ out) {
  int i = blockIdx.x * 256 + threadIdx.x;
  float4 v = ((const float4*)in)[i];
  ushort4 o;
  o.x = f2bf(v.x); o.y = f2bf(v.y); o.z = f2bf(v.z); o.w = f2bf(v.w);
  ((ushort4*)out)[i] = o;
}

// in[R][C] fp32 -> out[perm(C)][R] bf16. PERM=1: c=h*288+d*3+w -> w*768+h*96+d
template <int PERM>
__global__ __launch_bounds__(256) void transpose_f32_bf16(const float* __restrict__ in,
                                                          u16* __restrict__ out,
                                                          int R, int C) {
  __shared__ u16 tile[32][33];
  int tilesC = C >> 5;
  int bc = blockIdx.x % tilesC, br = blockIdx.x / tilesC;
  int tx = threadIdx.x & 31, ty = threadIdx.x >> 5;
#pragma unroll
  for (int i = 0; i < 4; ++i)
    tile[ty + i * 8][tx] = f2bf(in[(size_t)(br * 32 + ty + i * 8) * C + bc * 32 + tx]);
  __syncthreads();
#pragma unroll
  for (int i = 0; i < 4; ++i) {
    int c = bc * 32 + ty + i * 8;
    int orow;
    if constexpr (PERM) {
      int which = c % 3, h = c / 288, d = (c % 288) / 3;
      orow = which * 768 + h * 96 + d;
    } else {
      orow = c;
    }
    out[(size_t)orow * R + br * 32 + tx] = tile[tx][ty + i * 8];
  }
}

// ---------------------------------------------------------------------------
// 256x256 GEMM, BK=64, 8 waves (2x4), dbuf=2, template-faithful 4 phases/tile:
// {ds_reads; stage-half; barrier; lgkmcnt(0); sched_barrier; prio1 16-MFMA
// prio0; barrier}, one vmcnt(0)+barrier per tile boundary. XOR-swizzled LDS.
template <int EPI>
__global__ __launch_bounds__(512, 2) void gemm256(
    const u16* __restrict__ A, const u16* __restrict__ BT,
    const float* __restrict__ bias, int K, int lda, int ldb, int ldc,
    int tilesN, int cpx, size_t bstride, float* __restrict__ outf,
    u16* __restrict__ q_dst, u16* __restrict__ k_dst, u16* __restrict__ v_dst) {
  __shared__ u16 As[2][16384];
  __shared__ u16 Bs[2][16384];
  const int bid = blockIdx.x;
  const int swz = (bid & 7) * cpx + (bid >> 3);
  const int tr = swz / tilesN, tc = swz % tilesN;
  const int tid = threadIdx.x, lane = tid & 63, wv = tid >> 6;
  const int wr = wv >> 2, wc = wv & 3;
  const int l15 = lane & 15, lhi = lane >> 4;
  const int nt = K >> 6;
  const int region = tc / 3;                    // EPI=0: 0=q,1=k,2=v

  BT += (size_t)((unsigned)(tr * 256) >> 10) * bstride;   // per-batch B (EPI=1)

  const u16 *srcA[4], *srcB[4];
#pragma unroll
  for (int ch = 0; ch < 4; ++ch) {
    int g = ch * 512 + tid;
    int r = g >> 3;
    int c = (g & 7) ^ ((r >> 1) & 7);
    srcA[ch] = A  + (size_t)(tr * 256 + r) * lda + c * 8;
    srcB[ch] = BT + (size_t)(tc * 256 + r) * ldb + c * 8;
  }
  int offa[8], offb[4];
#pragma unroll
  for (int m = 0; m < 8; ++m) {
    int r = wr * 128 + m * 16 + l15;
    offa[m] = r * 64 + (lhi ^ ((r >> 1) & 7)) * 8;
  }
#pragma unroll
  for (int n = 0; n < 4; ++n) {
    int r = wc * 64 + n * 16 + l15;
    offb[n] = r * 64 + (lhi ^ ((r >> 1) & 7)) * 8;
  }

  // bias hoisted out of the epilogue (kills the per-element div/mod chain)
  float bv4[4];
#pragma unroll
  for (int n = 0; n < 4; ++n) {
    int colg = tc * 256 + wc * 64 + n * 16 + l15;
    if constexpr (EPI == 0) {
      int lcol = colg - region * 768;
      bv4[n] = bias[(lcol / 96) * 288 + (lcol % 96) * 3 + region];
    } else {
      bv4[n] = bias[colg];
    }
  }

#define STAGE_A(t_) do { u16* Ad_ = As[(t_) & 1]; int ko_ = (t_) * 64; \
    _Pragma("unroll") for (int ch = 0; ch < 4; ++ch) \
      GLD16(srcA[ch] + ko_, Ad_ + ((ch * 512 + wv * 64) * 8)); } while (0)
#define STAGE_B(t_) do { u16* Bd_ = Bs[(t_) & 1]; int ko_ = (t_) * 64; \
    _Pragma("unroll") for (int ch = 0; ch < 4; ++ch) \
      GLD16(srcB[ch] + ko_, Bd_ + ((ch * 512 + wv * 64) * 8)); } while (0)

  bf16x8 af[4][2], bfv[4][2];
#define RD_A(m_, slot_) do { \
    af[slot_][0] = *(const bf16x8*)&Ab[offa[m_]]; \
    af[slot_][1] = *(const bf16x8*)&Ab[offa[m_] ^ 32]; } while (0)
#define RD_B(n_) do { \
    bfv[n_][0] = *(const bf16x8*)&Bb[offb[n_]]; \
    bfv[n_][1] = *(const bf16x8*)&Bb[offb[n_] ^ 32]; } while (0)

  f32x4 acc[8][4] = {};
#define CLUSTER(MB, NB) do { \
    __builtin_amdgcn_s_setprio(1); \
    _Pragma("unroll") for (int mm = 0; mm < 4; ++mm) \
    _Pragma("unroll") for (int nn = 0; nn < 2; ++nn) \
    _Pragma("unroll") for (int ks = 0; ks < 2; ++ks) \
      acc[(MB) + mm][(NB) + nn] = __builtin_amdgcn_mfma_f32_16x16x32_bf16( \
          af[mm][ks], bfv[(NB) + nn][ks], acc[(MB) + mm][(NB) + nn], 0, 0, 0); \
    __builtin_amdgcn_s_setprio(0); } while (0)
#define WAIT_LGKM_PIN() do { \
    asm volatile("s_waitcnt lgkmcnt(0)" ::: "memory"); \
    __builtin_amdgcn_sched_barrier(0); } while (0)

  STAGE_A(0); STAGE_B(0);
  asm volatile("s_waitcnt vmcnt(0)" ::: "memory");
  __builtin_amdgcn_s_barrier();

  for (int t = 0; t < nt; ++t) {
    const u16* Ab = As[t & 1];
    const u16* Bb = Bs[t & 1];
    // ---- Ph0: reads for C(0,0..1) issued BEFORE the barrier; stage A-half
    RD_A(0, 0); RD_A(1, 1); RD_A(2, 2); RD_A(3, 3);
    RD_B(0); RD_B(1);
    if (t + 1 < nt) STAGE_A(t + 1);
    asm volatile("s_waitcnt lgkmcnt(8)" ::: "memory");
    __builtin_amdgcn_s_barrier();
    WAIT_LGKM_PIN();
    CLUSTER(0, 0);
    __builtin_amdgcn_s_barrier();
    // ---- Ph1: reads for C(0,2..3); stage B-half
    RD_B(2); RD_B(3);
    if (t + 1 < nt) STAGE_B(t + 1);
    __builtin_amdgcn_s_barrier();
    WAIT_LGKM_PIN();
    CLUSTER(0, 2);
    __builtin_amdgcn_s_barrier();
    // ---- Ph2: reads for C(4,*)
    RD_A(4, 0); RD_A(5, 1); RD_A(6, 2); RD_A(7, 3);
    __builtin_amdgcn_s_barrier();
    WAIT_LGKM_PIN();
    CLUSTER(4, 0);
    __builtin_amdgcn_s_barrier();
    // ---- Ph3: last cluster; tile-boundary certification of buf cur^1
    CLUSTER(4, 2);
    asm volatile("s_waitcnt vmcnt(0)" ::: "memory");
    __builtin_amdgcn_s_barrier();
  }
#undef STAGE_A
#undef STAGE_B
#undef RD_A
#undef RD_B
#undef CLUSTER
#undef WAIT_LGKM_PIN

  u16* dst16 = region == 0 ? q_dst : (region == 1 ? k_dst : v_dst);
#pragma unroll
  for (int m = 0; m < 8; ++m)
#pragma unroll
    for (int n = 0; n < 4; ++n) {
      int colg = tc * 256 + wc * 64 + n * 16 + l15;
      int lcol = colg - region * 768;
#pragma unroll
      for (int r = 0; r < 4; ++r) {
        int rowg = tr * 256 + wr * 128 + m * 16 + lhi * 4 + r;
        if constexpr (EPI == 0)
          dst16[(size_t)rowg * ldc + lcol] = f2bf(acc[m][n][r] + bv4[n]);
        else
          outf[(size_t)rowg * ldc + colg] = acc[m][n][r] + bv4[n];
      }
    }
}

// ---------------------------------------------------------------------------
// src[16384][768] (= [b][n][h*96+d]) -> dst[bh][d][n]  (LDS-tiled transpose)
__global__ __launch_bounds__(256) void kvtrans(const u16* __restrict__ src,
                                               u16* __restrict__ dst) {
  __shared__ u16 tile[32][33];
  int id = blockIdx.x;
  int ntile = id & 31;
  int dt = (id >> 5) % 3;
  int bh = id / 96;
  int b = bh >> 3, h = bh & 7;
  int tx = threadIdx.x & 31, ty = threadIdx.x >> 5;
  const u16* s = src + ((size_t)b * 1024 + ntile * 32) * 768 + h * 96 + dt * 32;
#pragma unroll
  for (int i = 0; i < 4; ++i)
    tile[ty + i * 8][tx] = s[(size_t)(ty + i * 8) * 768 + tx];
  __syncthreads();
  u16* dp = dst + (size_t)bh * 96 * 1024 + (size_t)(dt * 32) * 1024 + ntile * 32;
#pragma unroll
  for (int i = 0; i < 4; ++i)
    dp[(size_t)(ty + i * 8) * 1024 + tx] = tile[tx][ty + i * 8];
}

// ---------------------------------------------------------------------------
// M[bh][d][d'] = sum_n K[n,d] V[n,d']  from kT[bh][96][1024], vT[bh][96][1024].
__global__ __launch_bounds__(256) void mkern(const u16* __restrict__ kT,
                                             const u16* __restrict__ vT,
                                             u16* __restrict__ M) {
  const int bh = blockIdx.x;
  const int tid = threadIdx.x, lane = tid & 63, wv = tid >> 6;
  const int mh = wv >> 1, nh = wv & 1;
  const int l15 = lane & 15, lhi = lane >> 4;
  const u16* Ka = kT + (size_t)bh * 96 * 1024;
  const u16* Va = vT + (size_t)bh * 96 * 1024;
  f32x4 acc[3][3] = {};
#pragma unroll 4
  for (int ks = 0; ks < 32; ++ks) {
    bf16x8 a[3], bv[3];
#pragma unroll
    for (int mi = 0; mi < 3; ++mi)
      a[mi] = *(const bf16x8*)(Ka + (size_t)(mh * 48 + mi * 16 + l15) * 1024 + ks * 32 + lhi * 8);
#pragma unroll
    for (int nj = 0; nj < 3; ++nj)
      bv[nj] = *(const bf16x8*)(Va + (size_t)(nh * 48 + nj * 16 + l15) * 1024 + ks * 32 + lhi * 8);
#pragma unroll
    for (int mi = 0; mi < 3; ++mi)
#pragma unroll
      for (int nj = 0; nj < 3; ++nj)
        acc[mi][nj] = __builtin_amdgcn_mfma_f32_16x16x32_bf16(a[mi], bv[nj], acc[mi][nj], 0, 0, 0);
  }
#pragma unroll
  for (int mi = 0; mi < 3; ++mi)
#pragma unroll
    for (int nj = 0; nj < 3; ++nj)
#pragma unroll
      for (int r = 0; r < 4; ++r)
        M[(size_t)bh * 9216 + (size_t)(mh * 48 + mi * 16 + lhi * 4 + r) * 96 +
          nh * 48 + nj * 16 + l15] = f2bf(acc[mi][nj][r]);
}

// ---------------------------------------------------------------------------
// GT[b][f][h*96+d] = sum_{d'} Wfc[h*96+d', f] * M[bh][d][d']
__global__ __launch_bounds__(512) void gkern(const u16* __restrict__ wfcT,
                                             const u16* __restrict__ M,
                                             u16* __restrict__ GT) {
  const int bh = blockIdx.x;
  const int b = bh >> 3, h = bh & 7;
  const int tid = threadIdx.x, lane = tid & 63, wv = tid >> 6;
  const int l15 = lane & 15, lhi = lane >> 4;
  const u16* Mb = M + (size_t)bh * 9216;
  f32x4 acc[6][6] = {};
#pragma unroll
  for (int ks = 0; ks < 3; ++ks) {
    bf16x8 a[6], bv[6];
#pragma unroll
    for (int fi = 0; fi < 6; ++fi)
      a[fi] = *(const bf16x8*)(wfcT + (size_t)(wv * 96 + fi * 16 + l15) * 768 +
                               h * 96 + ks * 32 + lhi * 8);
#pragma unroll
    for (int nj = 0; nj < 6; ++nj)
      bv[nj] = *(const bf16x8*)(Mb + (size_t)(nj * 16 + l15) * 96 + ks * 32 + lhi * 8);
#pragma unroll
    for (int fi = 0; fi < 6; ++fi)
#pragma unroll
      for (int nj = 0; nj < 6; ++nj)
        acc[fi][nj] = __builtin_amdgcn_mfma_f32_16x16x32_bf16(a[fi], bv[nj], acc[fi][nj], 0, 0, 0);
  }
#pragma unroll
  for (int fi = 0; fi < 6; ++fi)
#pragma unroll
    for (int nj = 0; nj < 6; ++nj)
#pragma unroll
      for (int r = 0; r < 4; ++r)
        GT[(size_t)b * 589824 + (size_t)(wv * 96 + fi * 16 + lhi * 4 + r) * 768 +
           h * 96 + nj * 16 + l15] = f2bf(acc[fi][nj][r]);
}

// ---------------------------------------------------------------------------
extern "C" void kernel_launch(void* const* d_in, const int* in_sizes, int n_in,
                              void* d_out, int out_size, void* d_ws, size_t ws_size,
                              hipStream_t stream) {
  const float* x    = (const float*)d_in[0];
  const float* Wqkv = (const float*)d_in[1];
  const float* bqkv = (const float*)d_in[2];
  const float* Wfc  = (const float*)d_in[3];
  const float* bfc  = (const float*)d_in[4];
  float* out = (float*)d_out;

  char* ws = (char*)d_ws;
  size_t off = 0;
  auto alloc = [&](size_t bytes) {
    void* p = ws + off;
    off += (bytes + 255) & ~(size_t)255;
    return p;
  };
  u16* xz    = (u16*)alloc(16384ull * 768 * 2);   // x_bf16; later kT[bh][96][1024]
  u16* wqkvT = (u16*)alloc(2304ull * 768 * 2);    // later M[128][96][96]
  u16* wfcT  = (u16*)alloc(768ull * 768 * 2);
  u16* qb    = (u16*)alloc(16384ull * 768 * 2);   // Q dense [16384][768]
  u16* kb    = (u16*)alloc(16384ull * 768 * 2);   // K dense; later vT[bh][96][1024]
  u16* vb    = (u16*)alloc(16384ull * 768 * 2);   // V dense; later GT[16][768][768]

  cvt_f32_bf16<<<12288, 256, 0, stream>>>(x, xz);
  transpose_f32_bf16<1><<<(2304 / 32) * (768 / 32), 256, 0, stream>>>(Wqkv, wqkvT, 768, 2304);
  transpose_f32_bf16<0><<<(768 / 32) * (768 / 32), 256, 0, stream>>>(Wfc, wfcT, 768, 768);

  // QKV projection -> dense q/k/v buffers
  gemm256<0><<<576, 512, 0, stream>>>(xz, wqkvT, bqkv, 768, 768, 768, 768,
                                      9, 72, 0, nullptr, qb, kb, vb);

  kvtrans<<<12288, 256, 0, stream>>>(kb, xz);   // kT <- K^T   (xz dead)
  kvtrans<<<12288, 256, 0, stream>>>(vb, kb);   // vT <- V^T   (kb consumed above)

  mkern<<<128, 256, 0, stream>>>(xz, kb, (u16*)wqkvT);          // M = K^T V
  gkern<<<128, 512, 0, stream>>>(wfcT, (u16*)wqkvT, vb);        // GT_b = (M W_h)^T

  // out = Q @ GT_b^T + bfc   (per-batch B matrix)
  gemm256<1><<<192, 512, 0, stream>>>(qb, vb, bfc, 768, 768, 768, 768,
                                      3, 24, 589824ull, out, nullptr, nullptr, nullptr);
}